// Round 7
// baseline (217.646 us; speedup 1.0000x reference)
//
#include <hip/hip_runtime.h>
#include <math.h>

// NoRefRetIQANet: cosine top-K retrieval, two-phase.
// Phase 1 (approx): score[b,n] ~= dot(f16(q_b), f16(d_n)) via MFMA hh-term
//   only; DB norms from exact f32 sum-sq folded into staging conversion.
//   Error ~1e-5 in cos units; top-16 selection margin ~1.25e-3 (114 sigma).
// Phase 2 (exact): top-16 candidates per (m,b) re-scored in exact fp32
//   (dot and norm), ranked (value desc, idx asc) -> top-9 -> metrics gather.
// Round-7: BN=128, 512 thr / 8 waves (2qh x 4nh), K-step 64, ring-2 LDS
// (A 2x8KB + B 2x32KB = 80 KB -> 2 blocks/CU), counted vmcnt(5), all staging
// via global_load_lds (A from pre-packed swizzled hi, B raw f32 with
// source-side chunk swizzle). Staged bytes 599 MB vs round-6's 962 MB.
// ws: semp0[64][20000] f32, semp1, dstp, nsq0/1/d[20000], apack_sem(hi),
//     apack_dst(hi), idx_ws[128][16] int.
// d_out: [0,64) result, [64, 64+64*18) retrieved.

typedef _Float16 half8 __attribute__((ext_vector_type(8)));
typedef float    f32x4 __attribute__((ext_vector_type(4)));

#define NDB    20000
#define NQ     64
#define KSEM   4096
#define KDST   2048
#define KC     2048
#define NSTEP  (KC / 64)     // 32 steps of 64
#define BN2    128
#define NTILE2 157           // ceil(20000/128); tail rows clamped
#define K2     16            // rerank candidates per (m,b)

__device__ __forceinline__ void async_cp16(const void* g, void* l) {
    __builtin_amdgcn_global_load_lds(
        (const __attribute__((address_space(1))) void*)g,
        (__attribute__((address_space(3))) void*)l, 16, 0, 0);
}

// ---------------------------------------------------------------------------
// qsplit: fp32 queries -> fragment-ordered, bank-swizzled f16 HI pack.
// Unit u (16B = half8) within a 32-k section: u = 4*row + (((row>>1)&3)^kg);
// section = 256 units. (same swizzle as rounds 3-6, hi only)
// ---------------------------------------------------------------------------
__global__ __launch_bounds__(256) void qsplit_kernel(
    const float* __restrict__ fc, const float* __restrict__ fd,
    _Float16* __restrict__ apack_sem, _Float16* __restrict__ apack_dst)
{
    const int idx = (int)blockIdx.x * 256 + (int)threadIdx.x;
    const int NSEM8 = NQ * KSEM / 8;            // 32768
    const float* src; _Float16* dst; int row, g8, K;
    if (idx < NSEM8) { src = fc; dst = apack_sem; K = KSEM; row = idx >> 9; g8 = idx & 511; }
    else { const int j = idx - NSEM8; src = fd; dst = apack_dst; K = KDST; row = j >> 8; g8 = j & 255; }

    const float* p = src + (size_t)row * K + g8 * 8;
    const float4 v0 = ((const float4*)p)[0];
    const float4 v1 = ((const float4*)p)[1];
    const float xs[8] = {v0.x, v0.y, v0.z, v0.w, v1.x, v1.y, v1.z, v1.w};
    half8 hi;
    #pragma unroll
    for (int e = 0; e < 8; ++e) hi[e] = (_Float16)xs[e];
    const int sec = g8 >> 2, kg = g8 & 3;
    const int u = (row << 2) + (((row >> 1) & 3) ^ kg);
    ((half8*)dst)[sec * 256 + u] = hi;
}

// ---------------------------------------------------------------------------
// score: 471 blocks = 157 n-tiles x {sem kc0, sem kc1, dst}, uniform KC=2048.
// 512 thr / 8 waves; wave (qh = w>>2, nh = w&3): 32q x 32n tile of 64q x 128n.
// ---------------------------------------------------------------------------
__global__ __launch_bounds__(512, 4) void score_kernel(
    const float* __restrict__ sdb, const float* __restrict__ ddb,
    const _Float16* __restrict__ apack_sem, const _Float16* __restrict__ apack_dst,
    float* __restrict__ semp0, float* __restrict__ semp1, float* __restrict__ dstp,
    float* __restrict__ nsq0, float* __restrict__ nsq1, float* __restrict__ nsqd)
{
    // A: [buf][sec*2048 + u*8] halves, u<256; 2 bufs x 8 KB
    __shared__ __align__(16) _Float16 A_lds[2][4096];
    // B: [buf][sec*4096 + r*32 + cphys*4] floats; 2 bufs x 32 KB
    __shared__ __align__(16) float    B_lds[2][8192];

    const int tid  = threadIdx.x;
    const int lane = tid & 63, w = tid >> 6;
    const int bid  = (int)blockIdx.x;
    const int mkc  = bid / NTILE2;        // 0: sem kc0, 1: sem kc1, 2: dst
    const int nt   = bid % NTILE2;
    const int n0   = nt * BN2;

    const float* D; const _Float16* AP; float *SOUT, *NOUT; int Ks, koff;
    if (mkc == 0)      { D=sdb; AP=apack_sem; SOUT=semp0; NOUT=nsq0; Ks=KSEM; koff=0;  }
    else if (mkc == 1) { D=sdb; AP=apack_sem; SOUT=semp1; NOUT=nsq1; Ks=KSEM; koff=KC; }
    else               { D=ddb; AP=apack_dst; SOUT=dstp;  NOUT=nsqd; Ks=KDST; koff=0;  }

    // --- B staging: per wave, per section: 2 insts (q=0,1); unit u = w*128+q*64+lane
    int   rB[2], rgB[2];
    const float* bbase[2];
    #pragma unroll
    for (int q = 0; q < 2; ++q) {
        const int u = w * 128 + q * 64 + lane;
        const int r = u >> 3;
        const int csrc = (u & 7) ^ (r & 7);
        rB[q] = r;
        rgB[q] = (n0 + r < NDB) ? n0 + r : NDB - 1;
        bbase[q] = D + (size_t)rgB[q] * Ks + koff + csrc * 4;
    }
    // --- A staging: wave w stages section w>>2, units (w&3)*64 + lane
    const int secA = w >> 2;
    const uint4* abase = (const uint4*)AP + ((size_t)koff >> 5) * 256
                         + (size_t)secA * 256 + (w & 3) * 64 + lane;

    // --- compute map ---
    const int lr = lane & 15, kg = lane >> 4;
    const int qh = w >> 2, nh = w & 3;
    const int rowA0 = qh * 32 + lr, rowA1 = rowA0 + 16;
    const int uA0 = ((rowA0 << 2) + (((rowA0 >> 1) & 3) ^ kg)) * 8;
    const int uA1 = ((rowA1 << 2) + (((rowA1 >> 1) & 3) ^ kg)) * 8;
    const int rF0 = nh * 32 + lr, rF1 = rF0 + 16;
    const int oB00 = rF0 * 32 + (((kg * 2 + 0) ^ (rF0 & 7)) << 2);
    const int oB01 = rF0 * 32 + (((kg * 2 + 1) ^ (rF0 & 7)) << 2);
    const int oB10 = rF1 * 32 + (((kg * 2 + 0) ^ (rF1 & 7)) << 2);
    const int oB11 = rF1 * 32 + (((kg * 2 + 1) ^ (rF1 & 7)) << 2);

    f32x4 acc[2][2];
    const f32x4 zz = {0.f, 0.f, 0.f, 0.f};
    #pragma unroll
    for (int i = 0; i < 2; ++i)
        #pragma unroll
        for (int j = 0; j < 2; ++j) acc[i][j] = zz;
    float sq0 = 0.f, sq1 = 0.f;

    auto STAGE = [&](int s, int buf) {
        async_cp16(abase + (size_t)s * 512, &A_lds[buf][secA * 2048 + (w & 3) * 512]);
        #pragma unroll
        for (int sec = 0; sec < 2; ++sec) {
            const int kofs = (2 * s + sec) * 32;
            #pragma unroll
            for (int q = 0; q < 2; ++q) {
                async_cp16(bbase[q] + kofs,
                           &B_lds[buf][sec * 4096 + (w * 128 + q * 64) * 4]);
            }
        }
    };

    auto COMPUTE = [&](int buf) {
        #pragma unroll
        for (int sec = 0; sec < 2; ++sec) {
            const float*    Bb = &B_lds[buf][sec * 4096];
            const _Float16* Ab = &A_lds[buf][sec * 2048];
            half8 bh0, bh1;
            {
                const f32x4 p = *(const f32x4*)(Bb + oB00);
                const f32x4 q = *(const f32x4*)(Bb + oB01);
                const float xs[8] = {p[0], p[1], p[2], p[3], q[0], q[1], q[2], q[3]};
                #pragma unroll
                for (int e = 0; e < 8; ++e) {
                    sq0 = fmaf(xs[e], xs[e], sq0);
                    bh0[e] = (_Float16)xs[e];
                }
            }
            {
                const f32x4 p = *(const f32x4*)(Bb + oB10);
                const f32x4 q = *(const f32x4*)(Bb + oB11);
                const float xs[8] = {p[0], p[1], p[2], p[3], q[0], q[1], q[2], q[3]};
                #pragma unroll
                for (int e = 0; e < 8; ++e) {
                    sq1 = fmaf(xs[e], xs[e], sq1);
                    bh1[e] = (_Float16)xs[e];
                }
            }
            const half8 ah0 = *(const half8*)(Ab + uA0);
            const half8 ah1 = *(const half8*)(Ab + uA1);
            acc[0][0] = __builtin_amdgcn_mfma_f32_16x16x32_f16(ah0, bh0, acc[0][0], 0, 0, 0);
            acc[0][1] = __builtin_amdgcn_mfma_f32_16x16x32_f16(ah0, bh1, acc[0][1], 0, 0, 0);
            acc[1][0] = __builtin_amdgcn_mfma_f32_16x16x32_f16(ah1, bh0, acc[1][0], 0, 0, 0);
            acc[1][1] = __builtin_amdgcn_mfma_f32_16x16x32_f16(ah1, bh1, acc[1][1], 0, 0, 0);
        }
    };

    // prologue: 2 steps in flight (10 DMA-inst/wave outstanding)
    STAGE(0, 0); STAGE(1, 1);

    for (int s = 0; s < NSTEP; ++s) {
        if (s < NSTEP - 1) { asm volatile("s_waitcnt vmcnt(5)" ::: "memory"); }
        else               { asm volatile("s_waitcnt vmcnt(0)" ::: "memory"); }
        __builtin_amdgcn_s_barrier();      // step-s data visible to all waves
        COMPUTE(s & 1);
        __builtin_amdgcn_s_barrier();      // all waves done with buf s&1
        if (s + 2 < NSTEP) STAGE(s + 2, s & 1);
    }

    // norms (exact f32 sum-sq of raw B): lane covers cols {rF0, rF1}, its kg
    // k-slices; reduce over kg (xor 16,32); qh==0 waves write.
    sq0 += __shfl_xor(sq0, 16); sq0 += __shfl_xor(sq0, 32);
    sq1 += __shfl_xor(sq1, 16); sq1 += __shfl_xor(sq1, 32);
    if (qh == 0 && lane < 16) {
        const int nn0 = n0 + nh * 32 + lane;
        const int nn1 = nn0 + 16;
        if (nn0 < NDB) NOUT[nn0] = sq0;
        if (nn1 < NDB) NOUT[nn1] = sq1;
    }

    // C/D map: col=lane&15, row=(lane>>4)*4+reg (m89-verified)
    #pragma unroll
    for (int i = 0; i < 2; ++i)
        #pragma unroll
        for (int j = 0; j < 2; ++j) {
            const int n = n0 + nh * 32 + j * 16 + lr;
            if (n < NDB) {
                #pragma unroll
                for (int rr = 0; rr < 4; ++rr) {
                    const int q = qh * 32 + i * 16 + kg * 4 + rr;
                    SOUT[(size_t)q * NDB + n] = acc[i][j][rr];
                }
            }
        }
}

// ---------------------------------------------------------------------------
// topk16: EXACT top-16 per (m,b) by approx score; writes candidate indices.
// Comparator: value desc, index asc.
// ---------------------------------------------------------------------------
__global__ __launch_bounds__(256) void topk_kernel(
    const float* __restrict__ semp0, const float* __restrict__ semp1,
    const float* __restrict__ dstp,
    const float* __restrict__ nsq0, const float* __restrict__ nsq1,
    const float* __restrict__ nsqd,
    int* __restrict__ idx_ws)
{
    __shared__ float sv[256][K2];
    __shared__ int   si[256][K2];

    const int tid = threadIdx.x;
    const int b = (int)blockIdx.x & 63;
    const int m = (int)blockIdx.x >> 6;   // 0=sem, 1=dst

    float v[K2]; int ix[K2];
    #pragma unroll
    for (int k = 0; k < K2; ++k) { v[k] = -INFINITY; ix[k] = 0x7fffffff; }

    const size_t roff = (size_t)b * NDB;
    for (int i = tid; i < NDB; i += 256) {
        float sval;
        if (m == 0) {
            sval = (semp0[roff + i] + semp1[roff + i]) * (1.0f / sqrtf(nsq0[i] + nsq1[i]));
        } else {
            sval = dstp[roff + i] * (1.0f / sqrtf(nsqd[i]));
        }
        if (sval > v[0]) {
            bool bt[K2];
            bt[0] = true;
            #pragma unroll
            for (int j = 1; j < K2; ++j) bt[j] = sval > v[j];
            #pragma unroll
            for (int j = 0; j < K2 - 1; ++j) {
                v[j]  = bt[j+1] ? v[j+1]  : (bt[j] ? sval : v[j]);
                ix[j] = bt[j+1] ? ix[j+1] : (bt[j] ? i    : ix[j]);
            }
            v[K2-1]  = bt[K2-1] ? sval : v[K2-1];
            ix[K2-1] = bt[K2-1] ? i    : ix[K2-1];
        }
    }

    #pragma unroll
    for (int k = 0; k < K2; ++k) { sv[tid][k] = v[k]; si[tid][k] = ix[k]; }
    __syncthreads();

    for (int s2 = 128; s2 >= 1; s2 >>= 1) {
        if (tid < s2) {
            float rv[K2]; int ri[K2];
            int pa = K2 - 1, pb = K2 - 1;
            #pragma unroll
            for (int k = K2 - 1; k >= 0; --k) {
                const float va = sv[tid][pa];      const int ia = si[tid][pa];
                const float vb = sv[tid + s2][pb]; const int ib = si[tid + s2][pb];
                const bool takeA = (va > vb) || (va == vb && ia < ib);
                rv[k] = takeA ? va : vb;
                ri[k] = takeA ? ia : ib;
                if (takeA) --pa; else --pb;
            }
            #pragma unroll
            for (int k = 0; k < K2; ++k) { sv[tid][k] = rv[k]; si[tid][k] = ri[k]; }
        }
        __syncthreads();
    }

    if (tid < K2) idx_ws[(size_t)blockIdx.x * K2 + tid] = si[0][K2 - 1 - tid];
}

// ---------------------------------------------------------------------------
// rerank: exact fp32 cos for 16 candidates per (m,b); rank (desc, idx asc);
// top-9 -> metrics gather into retrieved[b][2j+m].
// ---------------------------------------------------------------------------
__global__ __launch_bounds__(256) void rerank_kernel(
    const float* __restrict__ fc, const float* __restrict__ fd,
    const float* __restrict__ sdb, const float* __restrict__ ddb,
    const int* __restrict__ idx_ws, const float* __restrict__ metrics,
    float* __restrict__ out_ret)
{
    __shared__ float cosv[K2];
    __shared__ int   cidx[K2];

    const int tid = threadIdx.x;
    const int lane = tid & 63, w = tid >> 6;
    const int bid = (int)blockIdx.x;
    const int b = bid & 63;
    const int m = bid >> 6;

    const float* Q  = (m == 0) ? fc + (size_t)b * KSEM : fd + (size_t)b * KDST;
    const float* DB = (m == 0) ? sdb : ddb;
    const int Ks = (m == 0) ? KSEM : KDST;
    const int nf4 = Ks / 4;

    for (int c = w; c < K2; c += 4) {
        const int idx = idx_ws[(size_t)bid * K2 + c];
        const float4* Q4 = (const float4*)Q;
        const float4* R4 = (const float4*)(DB + (size_t)idx * Ks);
        float dot = 0.f, sq = 0.f;
        for (int it = lane; it < nf4; it += 64) {
            const float4 qv = Q4[it];
            const float4 rv = R4[it];
            dot = fmaf(qv.x, rv.x, dot); sq = fmaf(rv.x, rv.x, sq);
            dot = fmaf(qv.y, rv.y, dot); sq = fmaf(rv.y, rv.y, sq);
            dot = fmaf(qv.z, rv.z, dot); sq = fmaf(rv.z, rv.z, sq);
            dot = fmaf(qv.w, rv.w, dot); sq = fmaf(rv.w, rv.w, sq);
        }
        #pragma unroll
        for (int off = 1; off < 64; off <<= 1) {
            dot += __shfl_xor(dot, off);
            sq  += __shfl_xor(sq,  off);
        }
        if (lane == 0) {
            cosv[c] = dot / sqrtf(sq);
            cidx[c] = idx;
        }
    }
    __syncthreads();

    if (tid < K2) {
        const float v = cosv[tid];
        const int   id = cidx[tid];
        int rank = 0;
        #pragma unroll
        for (int j = 0; j < K2; ++j)
            rank += (cosv[j] > v) || (cosv[j] == v && cidx[j] < id);
        if (rank < 9) out_ret[(size_t)b * 18 + 2 * rank + m] = metrics[id];
    }
}

// result[b] = mean(retrieved[b][0..17])
__global__ void finalize_kernel(float* __restrict__ d_out)
{
    const int b = threadIdx.x;
    const float* r = d_out + 64 + (size_t)b * 18;
    float s = 0.f;
    #pragma unroll
    for (int j = 0; j < 18; ++j) s += r[j];
    d_out[b] = s * (1.0f / 18.0f);
}

extern "C" void kernel_launch(void* const* d_in, const int* in_sizes, int n_in,
                              void* d_out, int out_size, void* d_ws, size_t ws_size,
                              hipStream_t stream)
{
    const float* fc  = (const float*)d_in[0];   // [64][4096]
    const float* fd  = (const float*)d_in[1];   // [64][2048]
    const float* sdb = (const float*)d_in[2];   // [20000][4096]
    const float* ddb = (const float*)d_in[3];   // [20000][2048]
    const float* met = (const float*)d_in[4];   // [20000]

    float* semp0 = (float*)d_ws;
    float* semp1 = semp0 + (size_t)NQ * NDB;
    float* dstp  = semp1 + (size_t)NQ * NDB;
    float* nsq0  = dstp  + (size_t)NQ * NDB;
    float* nsq1  = nsq0 + NDB;
    float* nsqd  = nsq1 + NDB;
    _Float16* apack_sem = (_Float16*)(nsqd + NDB);       // hi only: 512 KB
    _Float16* apack_dst = apack_sem + (size_t)NQ * KSEM; // hi only: 256 KB
    int* idx_ws = (int*)(apack_dst + (size_t)NQ * KDST); // 128*16 ints

    float* out = (float*)d_out;

    qsplit_kernel<<<dim3(192), dim3(256), 0, stream>>>(fc, fd, apack_sem, apack_dst);
    score_kernel<<<dim3(3 * NTILE2), dim3(512), 0, stream>>>(
        sdb, ddb, apack_sem, apack_dst, semp0, semp1, dstp, nsq0, nsq1, nsqd);
    topk_kernel<<<dim3(128), dim3(256), 0, stream>>>(
        semp0, semp1, dstp, nsq0, nsq1, nsqd, idx_ws);
    rerank_kernel<<<dim3(128), dim3(256), 0, stream>>>(
        fc, fd, sdb, ddb, idx_ws, met, out + 64);
    finalize_kernel<<<dim3(1), dim3(64), 0, stream>>>(out);
}